// Round 4
// baseline (1285.941 us; speedup 1.0000x reference)
//
#include <hip/hip_runtime.h>

// RGCN 2-layer forward, MI355X — v3: sort-by-(dst,rel) + aggregate-then-transform,
// all-fp32 weights (v2's bf16 W1 failed absmax 2.5e-2 > 2e-2).
// Per wave: 4 dsts batched; W transposed + XOR-swizzled in LDS for b128 reads.

#define NN 100000
#define EE 1600000
#define NREL 16
#define NBINS (NN * NREL)  // 1,600,000
#define SCAN_BLK 4096
#define NSCAN_BLKS ((NBINS + SCAN_BLK - 1) / SCAN_BLK)  // 391

// ---------------- histogram C[dst*16+t]++ ----------------
__global__ __launch_bounds__(256) void count_k(const int* __restrict__ ei,
                                               const int* __restrict__ et,
                                               unsigned* __restrict__ C) {
  int i = blockIdx.x * blockDim.x + threadIdx.x;
  int stride = gridDim.x * blockDim.x;
  for (; i < EE; i += stride) {
    int d = ei[EE + i];
    int t = et[i];
    atomicAdd(&C[d * NREL + t], 1u);
  }
}

// ---------------- scan level 1 ----------------
__global__ __launch_bounds__(256) void scan1_k(const unsigned* __restrict__ C,
                                               unsigned* __restrict__ part,
                                               unsigned* __restrict__ bsum) {
  __shared__ unsigned ssc[256];
  const int t = threadIdx.x, b = blockIdx.x;
  const int base = b * SCAN_BLK + t * 16;
  unsigned v[16];
  unsigned s = 0;
  const bool in = (base < NBINS);
  if (in) {
    const uint4* cp = reinterpret_cast<const uint4*>(C + base);
#pragma unroll
    for (int q = 0; q < 4; ++q) {
      uint4 u = cp[q];
      v[q * 4 + 0] = u.x; v[q * 4 + 1] = u.y; v[q * 4 + 2] = u.z; v[q * 4 + 3] = u.w;
      s += u.x + u.y + u.z + u.w;
    }
  } else {
#pragma unroll
    for (int q = 0; q < 16; ++q) v[q] = 0;
  }
  ssc[t] = s;
  __syncthreads();
  for (int off = 1; off < 256; off <<= 1) {
    unsigned add = (t >= off) ? ssc[t - off] : 0u;
    __syncthreads();
    ssc[t] += add;
    __syncthreads();
  }
  unsigned run = ssc[t] - s;
  if (in) {
#pragma unroll
    for (int q = 0; q < 16; ++q) { part[base + q] = run; run += v[q]; }
  }
  if (t == 255) bsum[b] = ssc[255];
}

// ---------------- scan level 2 ----------------
__global__ __launch_bounds__(512) void scan2_k(const unsigned* __restrict__ bsum,
                                               unsigned* __restrict__ boff) {
  __shared__ unsigned ssc[512];
  const int t = threadIdx.x;
  unsigned s = (t < NSCAN_BLKS) ? bsum[t] : 0u;
  ssc[t] = s;
  __syncthreads();
  for (int off = 1; off < 512; off <<= 1) {
    unsigned add = (t >= off) ? ssc[t - off] : 0u;
    __syncthreads();
    ssc[t] += add;
    __syncthreads();
  }
  if (t < NSCAN_BLKS) boff[t] = ssc[t] - s;
}

// ---------------- add offsets ----------------
__global__ __launch_bounds__(256) void addoff_k(const unsigned* __restrict__ part,
                                                const unsigned* __restrict__ boff,
                                                unsigned* __restrict__ keyptr,
                                                unsigned* __restrict__ cursor) {
  int i = blockIdx.x * blockDim.x + threadIdx.x;
  unsigned val = part[i] + boff[i >> 12];
  keyptr[i] = val;
  cursor[i] = val;
  if (i == 0) keyptr[NBINS] = EE;
}

// ---------------- scatter edges into sorted order ----------------
__global__ __launch_bounds__(256) void esort_k(const int* __restrict__ ei,
                                               const int* __restrict__ et,
                                               unsigned* __restrict__ cursor,
                                               int* __restrict__ sorted) {
  int i = blockIdx.x * blockDim.x + threadIdx.x;
  int stride = gridDim.x * blockDim.x;
  for (; i < EE; i += stride) {
    int s = ei[i];
    int d = ei[EE + i];
    int t = et[i];
    unsigned p = atomicAdd(&cursor[d * NREL + t], 1u);
    sorted[p] = s;
  }
}

// ---------------- stage 64x64 fp32: transpose + XOR swizzle (m214 recipe) ----------------
// physical float4 slot for (o, kq) is kq ^ (o&7); read side uses the same XOR.
__device__ __forceinline__ void stage64x64(const float* __restrict__ src,
                                           float* __restrict__ dst, int tid) {
#pragma unroll
  for (int s = tid; s < 1024; s += 512) {
    int o = s & 63, kq = s >> 6;
    float4 v;
    v.x = src[(kq * 4 + 0) * 64 + o];
    v.y = src[(kq * 4 + 1) * 64 + o];
    v.z = src[(kq * 4 + 2) * 64 + o];
    v.w = src[(kq * 4 + 3) * 64 + o];
    *reinterpret_cast<float4*>(&dst[o * 64 + ((kq ^ (o & 7)) << 2)]) = v;
  }
}

// ---------------- layer 1: h1[dst] = relu(emb@root1 + b1 + sum_r mean_r @ W1_r) ----------------
// 512 thr = 8 waves; 4 dsts per wave; grid 3125 (exact).
__global__ __launch_bounds__(512, 4) void layer1_k(const float* __restrict__ x,
                                                   const float* __restrict__ root,
                                                   const float* __restrict__ bias,
                                                   const float* __restrict__ W1,
                                                   const unsigned* __restrict__ keyptr,
                                                   const int* __restrict__ srcs,
                                                   float* __restrict__ h1) {
  __shared__ __align__(16) float rootT[4096];   // 16 KB
  __shared__ __align__(16) float WT[2][4096];   // 32 KB
  __shared__ __align__(16) float xbuf[8][4][64];// 8 KB   -> 56 KB total, 2 blocks/CU
  const int tid = threadIdx.x, wv = tid >> 6, lane = tid & 63;
  const int dst0 = blockIdx.x * 32 + wv * 4;

  stage64x64(root, rootT, tid);

  unsigned rowv[4];
  float acc[4];
  const int li = (lane < 16) ? lane : 16;  // lanes 0..16 hold the 17 segment ptrs
#pragma unroll
  for (int b = 0; b < 4; ++b) {
    rowv[b] = keyptr[(dst0 + b) * NREL + li];
    acc[b] = bias[lane];
    xbuf[wv][b][lane] = x[(long)(dst0 + b) * 64 + lane];
  }
  __syncthreads();

  // root matvec: acc[o] += sum_k x[k] * root[k][o]
#pragma unroll
  for (int kq = 0; kq < 16; ++kq) {
    float4 w4 = *reinterpret_cast<const float4*>(&rootT[lane * 64 + ((kq ^ (lane & 7)) << 2)]);
#pragma unroll
    for (int b = 0; b < 4; ++b) {
      float4 xq = *reinterpret_cast<const float4*>(&xbuf[wv][b][kq * 4]);
      acc[b] += xq.x * w4.x + xq.y * w4.y + xq.z * w4.z + xq.w * w4.w;
    }
  }

  for (int g = 0; g < 8; ++g) {
    __syncthreads();  // all waves done with previous WT
    stage64x64(W1 + (long)(2 * g) * 4096, WT[0], tid);
    stage64x64(W1 + (long)(2 * g + 1) * 4096, WT[1], tid);
    __syncthreads();
#pragma unroll
    for (int rr = 0; rr < 2; ++rr) {
      const int r = 2 * g + rr;
      int cs = 0;
#pragma unroll
      for (int b = 0; b < 4; ++b) {
        unsigned a0 = __shfl(rowv[b], r), a1 = __shfl(rowv[b], r + 1);
        int c = (int)(a1 - a0);
        cs |= c;
        float av = 0.f;
        for (unsigned e = a0; e < a1; ++e) av += x[(long)srcs[e] * 64 + lane];
        xbuf[wv][b][lane] = (c > 0) ? av * (1.0f / (float)c) : 0.f;
      }
      if (cs) {  // wave-uniform
#pragma unroll
        for (int kq = 0; kq < 16; ++kq) {
          float4 w4 = *reinterpret_cast<const float4*>(&WT[rr][lane * 64 + ((kq ^ (lane & 7)) << 2)]);
#pragma unroll
          for (int b = 0; b < 4; ++b) {
            float4 xq = *reinterpret_cast<const float4*>(&xbuf[wv][b][kq * 4]);
            acc[b] += xq.x * w4.x + xq.y * w4.y + xq.z * w4.z + xq.w * w4.w;
          }
        }
      }
    }
  }
#pragma unroll
  for (int b = 0; b < 4; ++b)
    h1[(long)(dst0 + b) * 64 + lane] = fmaxf(acc[b], 0.f);
}

// ---------------- layer 2: out = sigmoid(h1@root2 + b2 + sum_r mean_r @ W2_r) ----------------
// lanes = 4 k-chunks x 16 cols; 4 dsts per wave; all 16 W2 staged once.
__global__ __launch_bounds__(512, 4) void layer2_k(const float* __restrict__ h1,
                                                   const float* __restrict__ root2,
                                                   const float* __restrict__ bias2,
                                                   const float* __restrict__ W2,
                                                   const unsigned* __restrict__ keyptr,
                                                   const int* __restrict__ srcs,
                                                   float* __restrict__ out) {
  __shared__ __align__(16) float WL[16 * 1024]; // 64 KB, [r][k][o] no pad (4-way ok)
  __shared__ __align__(16) float rootL[1024];   // 4 KB
  __shared__ __align__(16) float xbuf[8][4][64];// 8 KB  -> 76 KB, 2 blocks/CU
  const int tid = threadIdx.x, wv = tid >> 6, lane = tid & 63;
  const int kk = lane >> 4, o = lane & 15;
  const int dst0 = blockIdx.x * 32 + wv * 4;

  // stage W2: 1024 rows of 16 floats; 2 rows per thread
#pragma unroll
  for (int row = tid; row < 1024; row += 512) {
    const float4* s4 = reinterpret_cast<const float4*>(W2 + (long)row * 16);
    float4* d4 = reinterpret_cast<float4*>(&WL[row * 16]);
#pragma unroll
    for (int q = 0; q < 4; ++q) d4[q] = s4[q];
  }
  if (tid < 64) {
    const float4* s4 = reinterpret_cast<const float4*>(root2 + (long)tid * 16);
    float4* d4 = reinterpret_cast<float4*>(&rootL[tid * 16]);
#pragma unroll
    for (int q = 0; q < 4; ++q) d4[q] = s4[q];
  }

  unsigned rowv[4];
  float acc[4];
  const int li = (lane < 16) ? lane : 16;
#pragma unroll
  for (int b = 0; b < 4; ++b) {
    rowv[b] = keyptr[(dst0 + b) * NREL + li];
    acc[b] = (kk == 0) ? bias2[o] : 0.f;
    xbuf[wv][b][lane] = h1[(long)(dst0 + b) * 64 + lane];
  }
  __syncthreads();

  // root matvec, k-split across kk
#pragma unroll
  for (int jq = 0; jq < 4; ++jq) {
    const int k0 = kk * 16 + jq * 4;
    float w0 = rootL[(k0 + 0) * 16 + o], w1 = rootL[(k0 + 1) * 16 + o];
    float w2 = rootL[(k0 + 2) * 16 + o], w3 = rootL[(k0 + 3) * 16 + o];
#pragma unroll
    for (int b = 0; b < 4; ++b) {
      float4 xq = *reinterpret_cast<const float4*>(&xbuf[wv][b][k0]);
      acc[b] += xq.x * w0 + xq.y * w1 + xq.z * w2 + xq.w * w3;
    }
  }

  for (int r = 0; r < NREL; ++r) {
    int cs = 0;
#pragma unroll
    for (int b = 0; b < 4; ++b) {
      unsigned a0 = __shfl(rowv[b], r), a1 = __shfl(rowv[b], r + 1);
      int c = (int)(a1 - a0);
      cs |= c;
      float av = 0.f;
      for (unsigned e = a0; e < a1; ++e) av += h1[(long)srcs[e] * 64 + lane];
      xbuf[wv][b][lane] = (c > 0) ? av * (1.0f / (float)c) : 0.f;
    }
    if (cs) {
      const float* Wr = &WL[r * 1024];
#pragma unroll
      for (int jq = 0; jq < 4; ++jq) {
        const int k0 = kk * 16 + jq * 4;
        float w0 = Wr[(k0 + 0) * 16 + o], w1 = Wr[(k0 + 1) * 16 + o];
        float w2 = Wr[(k0 + 2) * 16 + o], w3 = Wr[(k0 + 3) * 16 + o];
#pragma unroll
        for (int b = 0; b < 4; ++b) {
          float4 xq = *reinterpret_cast<const float4*>(&xbuf[wv][b][k0]);
          acc[b] += xq.x * w0 + xq.y * w1 + xq.z * w2 + xq.w * w3;
        }
      }
    }
  }
#pragma unroll
  for (int b = 0; b < 4; ++b) {
    float v = acc[b];
    v += __shfl_xor(v, 16);
    v += __shfl_xor(v, 32);
    if (lane < 16) out[(long)(dst0 + b) * 16 + lane] = 1.0f / (1.0f + expf(-v));
  }
}

extern "C" void kernel_launch(void* const* d_in, const int* in_sizes, int n_in,
                              void* d_out, int out_size, void* d_ws, size_t ws_size,
                              hipStream_t stream) {
  const int* ei = (const int*)d_in[0];
  const int* et = (const int*)d_in[1];
  const float* emb = (const float*)d_in[2];
  const float* W1 = (const float*)d_in[3];
  const float* root1 = (const float*)d_in[4];
  const float* bias1 = (const float*)d_in[5];
  const float* W2 = (const float*)d_in[6];
  const float* root2 = (const float*)d_in[7];
  const float* bias2 = (const float*)d_in[8];
  float* out = (float*)d_out;

  uint8_t* ws = (uint8_t*)d_ws;
  unsigned* C = (unsigned*)(ws + 0);                 // 6.40 MB
  unsigned* part = (unsigned*)(ws + 6400000);        // 6.40 MB
  unsigned* keyptr = (unsigned*)(ws + 12800000);     // 6.40 MB + sentinel
  unsigned* cursor = (unsigned*)(ws + 19200512);     // 6.40 MB
  int* sorted = (int*)(ws + 25600512);               // 6.40 MB
  unsigned* bsum = (unsigned*)(ws + 32000512);       // 2 KB
  unsigned* boff = (unsigned*)(ws + 32002560);       // 2 KB
  float* h1 = (float*)(ws + 32004608);               // 25.6 MB
  // total ~57.6 MB

  hipMemsetAsync(C, 0, (size_t)NBINS * 4, stream);
  count_k<<<2048, 256, 0, stream>>>(ei, et, C);
  scan1_k<<<NSCAN_BLKS, 256, 0, stream>>>(C, part, bsum);
  scan2_k<<<1, 512, 0, stream>>>(bsum, boff);
  addoff_k<<<NBINS / 256, 256, 0, stream>>>(part, boff, keyptr, cursor);
  esort_k<<<2048, 256, 0, stream>>>(ei, et, cursor, sorted);
  layer1_k<<<NN / 32, 512, 0, stream>>>(emb, root1, bias1, W1, keyptr, sorted, h1);
  layer2_k<<<NN / 32, 512, 0, stream>>>(h1, root2, bias2, W2, keyptr, sorted, out);
}

// Round 5
// 1268.253 us; speedup vs baseline: 1.0139x; 1.0139x over previous
//
#include <hip/hip_runtime.h>

// RGCN 2-layer forward, MI355X — v4: sort-by-(dst,rel) + aggregate-then-transform.
// vs v3: 8 dsts/wave, lane-parallel gather prefetch, root/W2 from L2 (not LDS),
// layer1 LDS 48KB (3 blocks/CU), layer2 barrier-free.

#define NN 100000
#define EE 1600000
#define NREL 16
#define NBINS (NN * NREL)  // 1,600,000
#define SCAN_BLK 4096
#define NSCAN_BLKS ((NBINS + SCAN_BLK - 1) / SCAN_BLK)  // 391

// ---------------- histogram C[dst*16+t]++ ----------------
__global__ __launch_bounds__(256) void count_k(const int* __restrict__ ei,
                                               const int* __restrict__ et,
                                               unsigned* __restrict__ C) {
  int i = blockIdx.x * blockDim.x + threadIdx.x;
  int stride = gridDim.x * blockDim.x;
  for (; i < EE; i += stride) {
    int d = ei[EE + i];
    int t = et[i];
    atomicAdd(&C[d * NREL + t], 1u);
  }
}

// ---------------- scan level 1 ----------------
__global__ __launch_bounds__(256) void scan1_k(const unsigned* __restrict__ C,
                                               unsigned* __restrict__ part,
                                               unsigned* __restrict__ bsum) {
  __shared__ unsigned ssc[256];
  const int t = threadIdx.x, b = blockIdx.x;
  const int base = b * SCAN_BLK + t * 16;
  unsigned v[16];
  unsigned s = 0;
  const bool in = (base < NBINS);
  if (in) {
    const uint4* cp = reinterpret_cast<const uint4*>(C + base);
#pragma unroll
    for (int q = 0; q < 4; ++q) {
      uint4 u = cp[q];
      v[q * 4 + 0] = u.x; v[q * 4 + 1] = u.y; v[q * 4 + 2] = u.z; v[q * 4 + 3] = u.w;
      s += u.x + u.y + u.z + u.w;
    }
  } else {
#pragma unroll
    for (int q = 0; q < 16; ++q) v[q] = 0;
  }
  ssc[t] = s;
  __syncthreads();
  for (int off = 1; off < 256; off <<= 1) {
    unsigned add = (t >= off) ? ssc[t - off] : 0u;
    __syncthreads();
    ssc[t] += add;
    __syncthreads();
  }
  unsigned run = ssc[t] - s;
  if (in) {
#pragma unroll
    for (int q = 0; q < 16; ++q) { part[base + q] = run; run += v[q]; }
  }
  if (t == 255) bsum[b] = ssc[255];
}

// ---------------- scan level 2 ----------------
__global__ __launch_bounds__(512) void scan2_k(const unsigned* __restrict__ bsum,
                                               unsigned* __restrict__ boff) {
  __shared__ unsigned ssc[512];
  const int t = threadIdx.x;
  unsigned s = (t < NSCAN_BLKS) ? bsum[t] : 0u;
  ssc[t] = s;
  __syncthreads();
  for (int off = 1; off < 512; off <<= 1) {
    unsigned add = (t >= off) ? ssc[t - off] : 0u;
    __syncthreads();
    ssc[t] += add;
    __syncthreads();
  }
  if (t < NSCAN_BLKS) boff[t] = ssc[t] - s;
}

// ---------------- add offsets ----------------
__global__ __launch_bounds__(256) void addoff_k(const unsigned* __restrict__ part,
                                                const unsigned* __restrict__ boff,
                                                unsigned* __restrict__ keyptr,
                                                unsigned* __restrict__ cursor) {
  int i = blockIdx.x * blockDim.x + threadIdx.x;
  unsigned val = part[i] + boff[i >> 12];
  keyptr[i] = val;
  cursor[i] = val;
  if (i == 0) keyptr[NBINS] = EE;
}

// ---------------- scatter edges into sorted order ----------------
__global__ __launch_bounds__(256) void esort_k(const int* __restrict__ ei,
                                               const int* __restrict__ et,
                                               unsigned* __restrict__ cursor,
                                               int* __restrict__ sorted) {
  int i = blockIdx.x * blockDim.x + threadIdx.x;
  int stride = gridDim.x * blockDim.x;
  for (; i < EE; i += stride) {
    int s = ei[i];
    int d = ei[EE + i];
    int t = et[i];
    unsigned p = atomicAdd(&cursor[d * NREL + t], 1u);
    sorted[p] = s;
  }
}

// ---------------- stage 2 relations transposed+swizzled into LDS ----------------
__device__ __forceinline__ void stage_rel_pair(const float* __restrict__ W,
                                               float* __restrict__ dst, int tid) {
#pragma unroll
  for (int s = tid; s < 2048; s += 512) {
    int o = s & 63, kq = (s >> 6) & 15, rr = s >> 10;
    const float* src = W + rr * 4096;
    float4 v;
    v.x = src[(kq * 4 + 0) * 64 + o];
    v.y = src[(kq * 4 + 1) * 64 + o];
    v.z = src[(kq * 4 + 2) * 64 + o];
    v.w = src[(kq * 4 + 3) * 64 + o];
    *reinterpret_cast<float4*>(&dst[rr * 4096 + o * 64 + ((kq ^ (o & 7)) << 2)]) = v;
  }
}

// ---------------- layer 1 ----------------
// 512 thr = 8 waves, 8 dsts/wave, 64 dsts/block, grid 1563 (ragged tail clamped).
__global__ __launch_bounds__(512, 4) void layer1_k(const float* __restrict__ x,
                                                   const float* __restrict__ root,
                                                   const float* __restrict__ bias,
                                                   const float* __restrict__ W1,
                                                   const unsigned* __restrict__ keyptr,
                                                   const int* __restrict__ srcs,
                                                   float* __restrict__ h1) {
  __shared__ __align__(16) float WT[2][4096];    // 32 KB: current rel pair
  __shared__ __align__(16) float xbuf[8][8][64]; // 16 KB, wave-private slices
  const int tid = threadIdx.x, wv = tid >> 6, lane = tid & 63;
  const int dst0 = blockIdx.x * 64 + wv * 8;
  const int li = (lane < 16) ? lane : 16;

  unsigned rowv[8];
  float acc[8];
#pragma unroll
  for (int b = 0; b < 8; ++b) {
    int d = dst0 + b; if (d > NN - 1) d = NN - 1;
    rowv[b] = keyptr[d * NREL + li];
    acc[b] = bias[lane];
    xbuf[wv][b][lane] = x[(long)d * 64 + lane];
  }

  // root matvec, W from global (L2-resident, coalesced 256B per k-row)
#pragma unroll
  for (int kq = 0; kq < 16; ++kq) {
    float4 w4;
    w4.x = root[(kq * 4 + 0) * 64 + lane];
    w4.y = root[(kq * 4 + 1) * 64 + lane];
    w4.z = root[(kq * 4 + 2) * 64 + lane];
    w4.w = root[(kq * 4 + 3) * 64 + lane];
#pragma unroll
    for (int b = 0; b < 8; ++b) {
      float4 xq = *reinterpret_cast<const float4*>(&xbuf[wv][b][kq * 4]);
      acc[b] += xq.x * w4.x + xq.y * w4.y + xq.z * w4.z + xq.w * w4.w;
    }
  }

  for (int p = 0; p < 8; ++p) {
    __syncthreads();  // all waves done reading previous WT
    stage_rel_pair(W1 + (long)p * 8192, &WT[0][0], tid);
    __syncthreads();  // WT staged
    const int r0 = 2 * p;
    float av1m[8];
    // gather both rels of the pair, all 8 dsts; lane-parallel prefetch of srcs
#pragma unroll
    for (int b = 0; b < 8; ++b) {
      unsigned a0 = __shfl(rowv[b], r0);
      unsigned mid = __shfl(rowv[b], r0 + 1);
      unsigned a2 = __shfl(rowv[b], r0 + 2);
      int cnt = (int)(a2 - a0);
      float av0 = 0.f, av1 = 0.f;
      int uu = 0;
      if (lane < cnt) uu = srcs[a0 + lane];
      int cl = cnt < 64 ? cnt : 64;
      for (int i = 0; i < cl; ++i) {
        int src = __shfl(uu, i);
        float xv = x[(long)src * 64 + lane];
        if ((int)(a0 + i) < (int)mid) av0 += xv; else av1 += xv;
      }
      for (int i = 64; i < cnt; ++i) {  // vanishingly rare tail
        int src = srcs[a0 + i];
        float xv = x[(long)src * 64 + lane];
        if ((int)(a0 + i) < (int)mid) av0 += xv; else av1 += xv;
      }
      int c0 = (int)(mid - a0), c1 = (int)(a2 - mid);
      xbuf[wv][b][lane] = c0 ? av0 * (1.0f / (float)c0) : 0.f;
      av1m[b] = c1 ? av1 * (1.0f / (float)c1) : 0.f;
    }
    // matvec rel r0
#pragma unroll
    for (int kq = 0; kq < 16; ++kq) {
      float4 w4 = *reinterpret_cast<const float4*>(
          &WT[0][lane * 64 + ((kq ^ (lane & 7)) << 2)]);
#pragma unroll
      for (int b = 0; b < 8; ++b) {
        float4 xq = *reinterpret_cast<const float4*>(&xbuf[wv][b][kq * 4]);
        acc[b] += xq.x * w4.x + xq.y * w4.y + xq.z * w4.z + xq.w * w4.w;
      }
    }
    // swap in second rel's means (wave-private xbuf: no barrier)
#pragma unroll
    for (int b = 0; b < 8; ++b) xbuf[wv][b][lane] = av1m[b];
    // matvec rel r0+1
#pragma unroll
    for (int kq = 0; kq < 16; ++kq) {
      float4 w4 = *reinterpret_cast<const float4*>(
          &WT[1][lane * 64 + ((kq ^ (lane & 7)) << 2)]);
#pragma unroll
      for (int b = 0; b < 8; ++b) {
        float4 xq = *reinterpret_cast<const float4*>(&xbuf[wv][b][kq * 4]);
        acc[b] += xq.x * w4.x + xq.y * w4.y + xq.z * w4.z + xq.w * w4.w;
      }
    }
  }
#pragma unroll
  for (int b = 0; b < 8; ++b)
    if (dst0 + b < NN) h1[(long)(dst0 + b) * 64 + lane] = fmaxf(acc[b], 0.f);
}

// ---------------- layer 2 ----------------
// W2/root2 from global (L2); LDS = xbuf only; zero barriers.
__global__ __launch_bounds__(512, 4) void layer2_k(const float* __restrict__ h1,
                                                   const float* __restrict__ root2,
                                                   const float* __restrict__ bias2,
                                                   const float* __restrict__ W2,
                                                   const unsigned* __restrict__ keyptr,
                                                   const int* __restrict__ srcs,
                                                   float* __restrict__ out) {
  __shared__ __align__(16) float xbuf[8][8][64];  // 16 KB
  const int tid = threadIdx.x, wv = tid >> 6, lane = tid & 63;
  const int kk = lane >> 4, o = lane & 15;
  const int dst0 = blockIdx.x * 64 + wv * 8;
  const int li = (lane < 16) ? lane : 16;

  unsigned rowv[8];
  float acc[8];
#pragma unroll
  for (int b = 0; b < 8; ++b) {
    int d = dst0 + b; if (d > NN - 1) d = NN - 1;
    rowv[b] = keyptr[d * NREL + li];
    acc[b] = (kk == 0) ? bias2[o] : 0.f;
    xbuf[wv][b][lane] = h1[(long)d * 64 + lane];
  }

  // root matvec (4-way k-split across kk)
#pragma unroll
  for (int jq = 0; jq < 4; ++jq) {
    const int k0 = kk * 16 + jq * 4;
    float w0 = root2[(k0 + 0) * 16 + o], w1 = root2[(k0 + 1) * 16 + o];
    float w2 = root2[(k0 + 2) * 16 + o], w3 = root2[(k0 + 3) * 16 + o];
#pragma unroll
    for (int b = 0; b < 8; ++b) {
      float4 xq = *reinterpret_cast<const float4*>(&xbuf[wv][b][k0]);
      acc[b] += xq.x * w0 + xq.y * w1 + xq.z * w2 + xq.w * w3;
    }
  }

  for (int p = 0; p < 8; ++p) {
    const int r0 = 2 * p;
    float av1m[8];
#pragma unroll
    for (int b = 0; b < 8; ++b) {
      unsigned a0 = __shfl(rowv[b], r0);
      unsigned mid = __shfl(rowv[b], r0 + 1);
      unsigned a2 = __shfl(rowv[b], r0 + 2);
      int cnt = (int)(a2 - a0);
      float av0 = 0.f, av1 = 0.f;
      int uu = 0;
      if (lane < cnt) uu = srcs[a0 + lane];
      int cl = cnt < 64 ? cnt : 64;
      for (int i = 0; i < cl; ++i) {
        int src = __shfl(uu, i);
        float xv = h1[(long)src * 64 + lane];
        if ((int)(a0 + i) < (int)mid) av0 += xv; else av1 += xv;
      }
      for (int i = 64; i < cnt; ++i) {
        int src = srcs[a0 + i];
        float xv = h1[(long)src * 64 + lane];
        if ((int)(a0 + i) < (int)mid) av0 += xv; else av1 += xv;
      }
      int c0 = (int)(mid - a0), c1 = (int)(a2 - mid);
      xbuf[wv][b][lane] = c0 ? av0 * (1.0f / (float)c0) : 0.f;
      av1m[b] = c1 ? av1 * (1.0f / (float)c1) : 0.f;
    }
#pragma unroll
    for (int rr = 0; rr < 2; ++rr) {
      if (rr == 1) {
#pragma unroll
        for (int b = 0; b < 8; ++b) xbuf[wv][b][lane] = av1m[b];
      }
      const float* Wr = W2 + (r0 + rr) * 1024;
#pragma unroll
      for (int jq = 0; jq < 4; ++jq) {
        const int k0 = kk * 16 + jq * 4;
        float w0 = Wr[(k0 + 0) * 16 + o], w1 = Wr[(k0 + 1) * 16 + o];
        float w2 = Wr[(k0 + 2) * 16 + o], w3 = Wr[(k0 + 3) * 16 + o];
#pragma unroll
        for (int b = 0; b < 8; ++b) {
          float4 xq = *reinterpret_cast<const float4*>(&xbuf[wv][b][k0]);
          acc[b] += xq.x * w0 + xq.y * w1 + xq.z * w2 + xq.w * w3;
        }
      }
    }
  }
#pragma unroll
  for (int b = 0; b < 8; ++b) {
    float v = acc[b];
    v += __shfl_xor(v, 16);
    v += __shfl_xor(v, 32);
    if (lane < 16 && dst0 + b < NN)
      out[(long)(dst0 + b) * 16 + lane] = 1.0f / (1.0f + expf(-v));
  }
}

extern "C" void kernel_launch(void* const* d_in, const int* in_sizes, int n_in,
                              void* d_out, int out_size, void* d_ws, size_t ws_size,
                              hipStream_t stream) {
  const int* ei = (const int*)d_in[0];
  const int* et = (const int*)d_in[1];
  const float* emb = (const float*)d_in[2];
  const float* W1 = (const float*)d_in[3];
  const float* root1 = (const float*)d_in[4];
  const float* bias1 = (const float*)d_in[5];
  const float* W2 = (const float*)d_in[6];
  const float* root2 = (const float*)d_in[7];
  const float* bias2 = (const float*)d_in[8];
  float* out = (float*)d_out;

  uint8_t* ws = (uint8_t*)d_ws;
  unsigned* C = (unsigned*)(ws + 0);                 // 6.40 MB
  unsigned* part = (unsigned*)(ws + 6400000);        // 6.40 MB
  unsigned* keyptr = (unsigned*)(ws + 12800000);     // 6.40 MB + sentinel
  unsigned* cursor = (unsigned*)(ws + 19200512);     // 6.40 MB
  int* sorted = (int*)(ws + 25600512);               // 6.40 MB
  unsigned* bsum = (unsigned*)(ws + 32000512);       // 2 KB
  unsigned* boff = (unsigned*)(ws + 32002560);       // 2 KB
  float* h1 = (float*)(ws + 32004608);               // 25.6 MB
  // total ~57.6 MB

  hipMemsetAsync(C, 0, (size_t)NBINS * 4, stream);
  count_k<<<2048, 256, 0, stream>>>(ei, et, C);
  scan1_k<<<NSCAN_BLKS, 256, 0, stream>>>(C, part, bsum);
  scan2_k<<<1, 512, 0, stream>>>(bsum, boff);
  addoff_k<<<NBINS / 256, 256, 0, stream>>>(part, boff, keyptr, cursor);
  esort_k<<<2048, 256, 0, stream>>>(ei, et, cursor, sorted);
  const int nblk = (NN + 63) / 64;  // 1563
  layer1_k<<<nblk, 512, 0, stream>>>(emb, root1, bias1, W1, keyptr, sorted, h1);
  layer2_k<<<nblk, 512, 0, stream>>>(h1, root2, bias2, W2, keyptr, sorted, out);
}

// Round 7
// 817.664 us; speedup vs baseline: 1.5727x; 1.5511x over previous
//
#include <hip/hip_runtime.h>

// RGCN 2-layer forward, MI355X — v6: dense transform (fp32 GEMM -> fp32 XR,
// L3-blocked by relation chunks) + dst-sorted gather, 8 independent chains/wave.
// v5's bf16 XR failed absmax (3.3e-2 > 2e-2): all-fp32 feature path.

#define NN 100000
#define EE 1600000
#define NREL 16
#define NBINS (NN * NREL)
#define SCAN_BLK 4096
#define NSCAN_BLKS ((NBINS + SCAN_BLK - 1) / SCAN_BLK)  // 391

// ---------------- histogram ----------------
__global__ __launch_bounds__(256) void count_k(const int* __restrict__ ei,
                                               const int* __restrict__ et,
                                               unsigned* __restrict__ C) {
  int i = blockIdx.x * blockDim.x + threadIdx.x;
  int stride = gridDim.x * blockDim.x;
  for (; i < EE; i += stride) {
    int d = ei[EE + i];
    int t = et[i];
    atomicAdd(&C[d * NREL + t], 1u);
  }
}

// ---------------- scan level 1 ----------------
__global__ __launch_bounds__(256) void scan1_k(const unsigned* __restrict__ C,
                                               unsigned* __restrict__ part,
                                               unsigned* __restrict__ bsum) {
  __shared__ unsigned ssc[256];
  const int t = threadIdx.x, b = blockIdx.x;
  const int base = b * SCAN_BLK + t * 16;
  unsigned v[16];
  unsigned s = 0;
  const bool in = (base < NBINS);
  if (in) {
    const uint4* cp = reinterpret_cast<const uint4*>(C + base);
#pragma unroll
    for (int q = 0; q < 4; ++q) {
      uint4 u = cp[q];
      v[q * 4 + 0] = u.x; v[q * 4 + 1] = u.y; v[q * 4 + 2] = u.z; v[q * 4 + 3] = u.w;
      s += u.x + u.y + u.z + u.w;
    }
  } else {
#pragma unroll
    for (int q = 0; q < 16; ++q) v[q] = 0;
  }
  ssc[t] = s;
  __syncthreads();
  for (int off = 1; off < 256; off <<= 1) {
    unsigned add = (t >= off) ? ssc[t - off] : 0u;
    __syncthreads();
    ssc[t] += add;
    __syncthreads();
  }
  unsigned run = ssc[t] - s;
  if (in) {
#pragma unroll
    for (int q = 0; q < 16; ++q) { part[base + q] = run; run += v[q]; }
  }
  if (t == 255) bsum[b] = ssc[255];
}

// ---------------- scan level 2 ----------------
__global__ __launch_bounds__(512) void scan2_k(const unsigned* __restrict__ bsum,
                                               unsigned* __restrict__ boff) {
  __shared__ unsigned ssc[512];
  const int t = threadIdx.x;
  unsigned s = (t < NSCAN_BLKS) ? bsum[t] : 0u;
  ssc[t] = s;
  __syncthreads();
  for (int off = 1; off < 512; off <<= 1) {
    unsigned add = (t >= off) ? ssc[t - off] : 0u;
    __syncthreads();
    ssc[t] += add;
    __syncthreads();
  }
  if (t < NSCAN_BLKS) boff[t] = ssc[t] - s;
}

// ---------------- add offsets ----------------
__global__ __launch_bounds__(256) void addoff_k(const unsigned* __restrict__ part,
                                                const unsigned* __restrict__ boff,
                                                unsigned* __restrict__ keyptr,
                                                unsigned* __restrict__ cursor) {
  int i = blockIdx.x * blockDim.x + threadIdx.x;
  unsigned val = part[i] + boff[i >> 12];
  keyptr[i] = val;
  cursor[i] = val;
  if (i == 0) keyptr[NBINS] = EE;
}

// ---------------- scatter edges into sorted order; emit {rowidx, rcp} ----------------
__global__ __launch_bounds__(256) void esort_k(const int* __restrict__ ei,
                                               const int* __restrict__ et,
                                               const unsigned* __restrict__ C,
                                               unsigned* __restrict__ cursor,
                                               uint2* __restrict__ edata) {
  int i = blockIdx.x * blockDim.x + threadIdx.x;
  int stride = gridDim.x * blockDim.x;
  for (; i < EE; i += stride) {
    int s = ei[i];
    int d = ei[EE + i];
    int t = et[i];
    unsigned bin = (unsigned)d * NREL + t;
    unsigned p = atomicAdd(&cursor[bin], 1u);
    float rc = 1.0f / (float)C[bin];
    edata[p] = make_uint2((unsigned)(t * NN + s), __float_as_uint(rc));
  }
}

// ---------------- GEMM: OUT[rel][row][DOUT] = A[row][0:64] @ B[rel] (fp32 out) ----------------
template <int DOUT, bool ROOT>
__global__ __launch_bounds__(256) void gemm_k(const float* __restrict__ A,
                                              const float* __restrict__ B,
                                              const float* __restrict__ bias,
                                              float* __restrict__ OUT) {
  __shared__ float xT[64][64];
  __shared__ float Wl[64 * DOUT];
  const int tid = threadIdx.x;
  const long row0 = (long)blockIdx.x * 64;
  const int rel = blockIdx.y;
  const float* Bp = B + (long)rel * 64 * DOUT;

#pragma unroll
  for (int i = 0; i < 4; ++i) {
    int idx = tid + i * 256;
    int r = idx & 63, kq = idx >> 6;
    float4 v = make_float4(0.f, 0.f, 0.f, 0.f);
    long g = row0 + r;
    if (g < (long)NN) v = *reinterpret_cast<const float4*>(A + g * 64 + kq * 4);
    xT[kq * 4 + 0][r] = v.x;
    xT[kq * 4 + 1][r] = v.y;
    xT[kq * 4 + 2][r] = v.z;
    xT[kq * 4 + 3][r] = v.w;
  }
  for (int idx = tid * 4; idx < 64 * DOUT; idx += 1024)
    *reinterpret_cast<float4*>(&Wl[idx]) = *reinterpret_cast<const float4*>(Bp + idx);
  __syncthreads();

  if (DOUT == 64) {
    const int rg = tid >> 4, cg = tid & 15;
    float acc[4][4] = {};
#pragma unroll 16
    for (int k = 0; k < 64; ++k) {
      float4 xv = *reinterpret_cast<const float4*>(&xT[k][rg * 4]);
      float4 wv = *reinterpret_cast<const float4*>(&Wl[k * 64 + cg * 4]);
      acc[0][0] += xv.x * wv.x; acc[0][1] += xv.x * wv.y; acc[0][2] += xv.x * wv.z; acc[0][3] += xv.x * wv.w;
      acc[1][0] += xv.y * wv.x; acc[1][1] += xv.y * wv.y; acc[1][2] += xv.y * wv.z; acc[1][3] += xv.y * wv.w;
      acc[2][0] += xv.z * wv.x; acc[2][1] += xv.z * wv.y; acc[2][2] += xv.z * wv.z; acc[2][3] += xv.z * wv.w;
      acc[3][0] += xv.w * wv.x; acc[3][1] += xv.w * wv.y; acc[3][2] += xv.w * wv.z; acc[3][3] += xv.w * wv.w;
    }
#pragma unroll
    for (int i = 0; i < 4; ++i) {
      long grow = row0 + rg * 4 + i;
      if (grow >= (long)NN) continue;
      float4 o;
      o.x = acc[i][0]; o.y = acc[i][1]; o.z = acc[i][2]; o.w = acc[i][3];
      if (ROOT) {
        o.x += bias[cg * 4 + 0]; o.y += bias[cg * 4 + 1];
        o.z += bias[cg * 4 + 2]; o.w += bias[cg * 4 + 3];
        *reinterpret_cast<float4*>(OUT + grow * 64 + cg * 4) = o;
      } else {
        *reinterpret_cast<float4*>(OUT + ((long)rel * NN + grow) * 64 + cg * 4) = o;
      }
    }
  } else {  // DOUT == 16
    const int c0 = (tid & 7) * 2, r0 = (tid >> 3) * 2;
    float acc[2][2] = {};
#pragma unroll 16
    for (int k = 0; k < 64; ++k) {
      float2 xv = *reinterpret_cast<const float2*>(&xT[k][r0]);
      float2 wv = *reinterpret_cast<const float2*>(&Wl[k * 16 + c0]);
      acc[0][0] += xv.x * wv.x; acc[0][1] += xv.x * wv.y;
      acc[1][0] += xv.y * wv.x; acc[1][1] += xv.y * wv.y;
    }
#pragma unroll
    for (int i = 0; i < 2; ++i) {
      long grow = row0 + r0 + i;
      if (grow >= (long)NN) continue;
      float2 o;
      o.x = acc[i][0]; o.y = acc[i][1];
      if (ROOT) {
        o.x += bias[c0 + 0]; o.y += bias[c0 + 1];
        *reinterpret_cast<float2*>(OUT + grow * 16 + c0) = o;
      } else {
        *reinterpret_cast<float2*>(OUT + ((long)rel * NN + grow) * 16 + c0) = o;
      }
    }
  }
}

// ---------------- gather layer 1: h1[d] (+)= sum_e XR[row_e]*rcp_e ----------------
// 4 waves/block, 8 dsts/wave, 2 edges/step (fp32 row = 256B = 32 lanes x float2).
__global__ __launch_bounds__(256) void gather1_k(float* __restrict__ h1,
                                                 const float* __restrict__ XR,
                                                 const unsigned* __restrict__ keyptr,
                                                 const uint2* __restrict__ edata,
                                                 int rlo, int rhi, int lastpass) {
  const int tid = threadIdx.x, wv = tid >> 6, lane = tid & 63;
  const int half = lane >> 5, dim2 = lane & 31;
  const int dst0 = blockIdx.x * 32 + wv * 8;
  const long rbase = -(long)rlo * NN;

  unsigned a0[8], a1[8];
  float2 acc[8];
  int maxc = 0;
#pragma unroll
  for (int b = 0; b < 8; ++b) {
    int d = dst0 + b; if (d > NN - 1) d = NN - 1;
    a0[b] = keyptr[d * NREL + rlo];
    a1[b] = keyptr[d * NREL + rhi];
    int c = (int)(a1[b] - a0[b]);
    maxc = c > maxc ? c : maxc;
    acc[b].x = 0.f; acc[b].y = 0.f;
  }

  for (int s2 = 0; s2 < maxc; s2 += 2) {
#pragma unroll
    for (int b = 0; b < 8; ++b) {
      if ((unsigned)s2 < a1[b] - a0[b]) {
        unsigned e = a0[b] + (unsigned)s2 + (unsigned)half;
        bool valid = e < a1[b];
        unsigned ec = valid ? e : a1[b] - 1u;
        uint2 v = edata[ec];
        float rc = valid ? __uint_as_float(v.y) : 0.f;
        long row = (long)v.x + rbase;
        float2 xv = *reinterpret_cast<const float2*>(&XR[row * 64 + dim2 * 2]);
        acc[b].x += xv.x * rc;
        acc[b].y += xv.y * rc;
      }
    }
  }

#pragma unroll
  for (int b = 0; b < 8; ++b) {
    acc[b].x += __shfl_xor(acc[b].x, 32);
    acc[b].y += __shfl_xor(acc[b].y, 32);
    int d = dst0 + b;
    if (d < NN && lane < 32) {
      float2 base = *reinterpret_cast<const float2*>(&h1[(long)d * 64 + lane * 2]);
      float vx = base.x + acc[b].x, vy = base.y + acc[b].y;
      if (lastpass) { vx = fmaxf(vx, 0.f); vy = fmaxf(vy, 0.f); }
      float2 o; o.x = vx; o.y = vy;
      *reinterpret_cast<float2*>(&h1[(long)d * 64 + lane * 2]) = o;
    }
  }
}

// ---------------- gather layer 2: out[d] (+)= sum_e XR2[row_e]*rcp_e ----------------
// 8 dsts/wave, 4 edges/step (fp32 row = 64B = 16 lanes x float).
__global__ __launch_bounds__(256) void gather2_k(float* __restrict__ out,
                                                 const float* __restrict__ XR,
                                                 const unsigned* __restrict__ keyptr,
                                                 const uint2* __restrict__ edata,
                                                 int rlo, int rhi, int lastpass) {
  const int tid = threadIdx.x, wv = tid >> 6, lane = tid & 63;
  const int slot = lane >> 4, dp = lane & 15;
  const int dst0 = blockIdx.x * 32 + wv * 8;
  const long rbase = -(long)rlo * NN;

  unsigned a0[8], a1[8];
  float acc[8];
  int maxc = 0;
#pragma unroll
  for (int b = 0; b < 8; ++b) {
    int d = dst0 + b; if (d > NN - 1) d = NN - 1;
    a0[b] = keyptr[d * NREL + rlo];
    a1[b] = keyptr[d * NREL + rhi];
    int c = (int)(a1[b] - a0[b]);
    maxc = c > maxc ? c : maxc;
    acc[b] = 0.f;
  }

  for (int s4 = 0; s4 < maxc; s4 += 4) {
#pragma unroll
    for (int b = 0; b < 8; ++b) {
      if ((unsigned)s4 < a1[b] - a0[b]) {
        unsigned e = a0[b] + (unsigned)s4 + (unsigned)slot;
        bool valid = e < a1[b];
        unsigned ec = valid ? e : a1[b] - 1u;
        uint2 v = edata[ec];
        float rc = valid ? __uint_as_float(v.y) : 0.f;
        long row = (long)v.x + rbase;
        acc[b] += XR[row * 16 + dp] * rc;
      }
    }
  }

#pragma unroll
  for (int b = 0; b < 8; ++b) {
    acc[b] += __shfl_xor(acc[b], 16);
    acc[b] += __shfl_xor(acc[b], 32);
    int d = dst0 + b;
    if (d < NN && lane < 16) {
      float v = out[(long)d * 16 + lane] + acc[b];
      if (lastpass) v = 1.0f / (1.0f + expf(-v));
      out[(long)d * 16 + lane] = v;
    }
  }
}

extern "C" void kernel_launch(void* const* d_in, const int* in_sizes, int n_in,
                              void* d_out, int out_size, void* d_ws, size_t ws_size,
                              hipStream_t stream) {
  const int* ei = (const int*)d_in[0];
  const int* et = (const int*)d_in[1];
  const float* emb = (const float*)d_in[2];
  const float* W1 = (const float*)d_in[3];
  const float* root1 = (const float*)d_in[4];
  const float* bias1 = (const float*)d_in[5];
  const float* W2 = (const float*)d_in[6];
  const float* root2 = (const float*)d_in[7];
  const float* bias2 = (const float*)d_in[8];
  float* out = (float*)d_out;

  uint8_t* ws = (uint8_t*)d_ws;
  unsigned* C = (unsigned*)(ws + 0);              // 6.4 MB
  unsigned* part = (unsigned*)(ws + 6400000);     // 6.4 MB
  unsigned* keyptr = (unsigned*)(ws + 12800000);  // 6.4 MB + sentinel
  unsigned* cursor = (unsigned*)(ws + 19200512);  // 6.4 MB
  uint2* edata = (uint2*)(ws + 25600512);         // 12.8 MB
  unsigned* bsum = (unsigned*)(ws + 38400512);    // 2 KB
  unsigned* boff = (unsigned*)(ws + 38402560);    // 2 KB
  float* h1 = (float*)(ws + 38404608);            // 25.6 MB
  float* XR = (float*)(ws + 64004608);            // G*25.6 MB (L1) / G*6.4 MB (L2)

  long avail = (long)ws_size - 64004608L;
  int G1 = (int)(avail / 25600000L); if (G1 < 1) G1 = 1; if (G1 > 4) G1 = 4;
  int G2 = (int)(avail / 6400000L);  if (G2 < 1) G2 = 1; if (G2 > 16) G2 = 16;

  const int nrow = (NN + 63) / 64;  // 1563
  const int ngat = (NN + 31) / 32;  // 3125

  hipMemsetAsync(C, 0, (size_t)NBINS * 4, stream);
  count_k<<<2048, 256, 0, stream>>>(ei, et, C);
  scan1_k<<<NSCAN_BLKS, 256, 0, stream>>>(C, part, bsum);
  scan2_k<<<1, 512, 0, stream>>>(bsum, boff);
  addoff_k<<<NBINS / 256, 256, 0, stream>>>(part, boff, keyptr, cursor);
  esort_k<<<2048, 256, 0, stream>>>(ei, et, C, cursor, edata);

  // ---- layer 1: root + relation chunks (XR L3-resident per chunk) ----
  gemm_k<64, true><<<dim3(nrow, 1), 256, 0, stream>>>(emb, root1, bias1, h1);
  for (int rlo = 0; rlo < NREL; rlo += G1) {
    int rhi = rlo + G1 > NREL ? NREL : rlo + G1;
    gemm_k<64, false><<<dim3(nrow, rhi - rlo), 256, 0, stream>>>(
        emb, W1 + (long)rlo * 64 * 64, nullptr, XR);
    gather1_k<<<ngat, 256, 0, stream>>>(h1, XR, keyptr, edata, rlo, rhi,
                                        rhi == NREL ? 1 : 0);
  }

  // ---- layer 2 ----
  gemm_k<16, true><<<dim3(nrow, 1), 256, 0, stream>>>(h1, root2, bias2, out);
  for (int rlo = 0; rlo < NREL; rlo += G2) {
    int rhi = rlo + G2 > NREL ? NREL : rlo + G2;
    gemm_k<16, false><<<dim3(nrow, rhi - rlo), 256, 0, stream>>>(
        h1, W2 + (long)rlo * 64 * 16, nullptr, XR);
    gather2_k<<<ngat, 256, 0, stream>>>(out, XR, keyptr, edata, rlo, rhi,
                                        rhi == NREL ? 1 : 0);
  }
}

// Round 8
// 769.548 us; speedup vs baseline: 1.6710x; 1.0625x over previous
//
#include <hip/hip_runtime.h>
#include <hip/hip_fp16.h>

// RGCN 2-layer forward, MI355X — v7: dense transform -> fp16 XR (halves the
// dominant XR write+read traffic vs v6's fp32; fp16 (2^-11) is 8x finer than
// the bf16 that failed absmax) + rel-loop GEMM (A-tile staged once per chunk)
// + dst-sorted gather with 8 independent chains/wave (unchanged from v6).

#define NN 100000
#define EE 1600000
#define NREL 16
#define NBINS (NN * NREL)
#define SCAN_BLK 4096
#define NSCAN_BLKS ((NBINS + SCAN_BLK - 1) / SCAN_BLK)  // 391

// ---------------- histogram ----------------
__global__ __launch_bounds__(256) void count_k(const int* __restrict__ ei,
                                               const int* __restrict__ et,
                                               unsigned* __restrict__ C) {
  int i = blockIdx.x * blockDim.x + threadIdx.x;
  int stride = gridDim.x * blockDim.x;
  for (; i < EE; i += stride) {
    int d = ei[EE + i];
    int t = et[i];
    atomicAdd(&C[d * NREL + t], 1u);
  }
}

// ---------------- scan level 1 ----------------
__global__ __launch_bounds__(256) void scan1_k(const unsigned* __restrict__ C,
                                               unsigned* __restrict__ part,
                                               unsigned* __restrict__ bsum) {
  __shared__ unsigned ssc[256];
  const int t = threadIdx.x, b = blockIdx.x;
  const int base = b * SCAN_BLK + t * 16;
  unsigned v[16];
  unsigned s = 0;
  const bool in = (base < NBINS);
  if (in) {
    const uint4* cp = reinterpret_cast<const uint4*>(C + base);
#pragma unroll
    for (int q = 0; q < 4; ++q) {
      uint4 u = cp[q];
      v[q * 4 + 0] = u.x; v[q * 4 + 1] = u.y; v[q * 4 + 2] = u.z; v[q * 4 + 3] = u.w;
      s += u.x + u.y + u.z + u.w;
    }
  } else {
#pragma unroll
    for (int q = 0; q < 16; ++q) v[q] = 0;
  }
  ssc[t] = s;
  __syncthreads();
  for (int off = 1; off < 256; off <<= 1) {
    unsigned add = (t >= off) ? ssc[t - off] : 0u;
    __syncthreads();
    ssc[t] += add;
    __syncthreads();
  }
  unsigned run = ssc[t] - s;
  if (in) {
#pragma unroll
    for (int q = 0; q < 16; ++q) { part[base + q] = run; run += v[q]; }
  }
  if (t == 255) bsum[b] = ssc[255];
}

// ---------------- scan level 2 ----------------
__global__ __launch_bounds__(512) void scan2_k(const unsigned* __restrict__ bsum,
                                               unsigned* __restrict__ boff) {
  __shared__ unsigned ssc[512];
  const int t = threadIdx.x;
  unsigned s = (t < NSCAN_BLKS) ? bsum[t] : 0u;
  ssc[t] = s;
  __syncthreads();
  for (int off = 1; off < 512; off <<= 1) {
    unsigned add = (t >= off) ? ssc[t - off] : 0u;
    __syncthreads();
    ssc[t] += add;
    __syncthreads();
  }
  if (t < NSCAN_BLKS) boff[t] = ssc[t] - s;
}

// ---------------- add offsets ----------------
__global__ __launch_bounds__(256) void addoff_k(const unsigned* __restrict__ part,
                                                const unsigned* __restrict__ boff,
                                                unsigned* __restrict__ keyptr,
                                                unsigned* __restrict__ cursor) {
  int i = blockIdx.x * blockDim.x + threadIdx.x;
  unsigned val = part[i] + boff[i >> 12];
  keyptr[i] = val;
  cursor[i] = val;
  if (i == 0) keyptr[NBINS] = EE;
}

// ---------------- scatter edges into sorted order; emit {rowidx, rcp} ----------------
__global__ __launch_bounds__(256) void esort_k(const int* __restrict__ ei,
                                               const int* __restrict__ et,
                                               const unsigned* __restrict__ C,
                                               unsigned* __restrict__ cursor,
                                               uint2* __restrict__ edata) {
  int i = blockIdx.x * blockDim.x + threadIdx.x;
  int stride = gridDim.x * blockDim.x;
  for (; i < EE; i += stride) {
    int s = ei[i];
    int d = ei[EE + i];
    int t = et[i];
    unsigned bin = (unsigned)d * NREL + t;
    unsigned p = atomicAdd(&cursor[bin], 1u);
    float rc = 1.0f / (float)C[bin];
    edata[p] = make_uint2((unsigned)(t * NN + s), __float_as_uint(rc));
  }
}

// ---------------- fp16 pack/unpack ----------------
__device__ __forceinline__ unsigned pack_h2(float a, float b) {
  __half2 h = __floats2half2_rn(a, b);
  return *reinterpret_cast<unsigned*>(&h);
}
__device__ __forceinline__ float2 unpack_h2(unsigned u) {
  __half2 h = *reinterpret_cast<__half2*>(&u);
  return __half22float2(h);
}

// ---------------- GEMM: for rel in chunk: OUT[rel][row][DOUT] = A[row] @ B[rel] ----------------
// A-tile staged ONCE per block, reused across the chunk's relations.
// ROOT: fp32 out + bias (nrel==1). Else: fp16-packed XR out.
template <int DOUT, bool ROOT>
__global__ __launch_bounds__(256) void gemm_k(const float* __restrict__ A,
                                              const float* __restrict__ B,
                                              const float* __restrict__ bias,
                                              void* __restrict__ OUTv, int nrel) {
  __shared__ float xT[64][64];
  __shared__ float Wl[64 * DOUT];
  const int tid = threadIdx.x;
  const long row0 = (long)blockIdx.x * 64;

#pragma unroll
  for (int i = 0; i < 4; ++i) {
    int idx = tid + i * 256;
    int r = idx & 63, kq = idx >> 6;
    float4 v = make_float4(0.f, 0.f, 0.f, 0.f);
    long g = row0 + r;
    if (g < (long)NN) v = *reinterpret_cast<const float4*>(A + g * 64 + kq * 4);
    xT[kq * 4 + 0][r] = v.x;
    xT[kq * 4 + 1][r] = v.y;
    xT[kq * 4 + 2][r] = v.z;
    xT[kq * 4 + 3][r] = v.w;
  }

  for (int rel = 0; rel < nrel; ++rel) {
    __syncthreads();  // guards xT staging (rel==0) and previous Wl use (rel>0)
    const float* Bp = B + (long)rel * 64 * DOUT;
    for (int idx = tid * 4; idx < 64 * DOUT; idx += 1024)
      *reinterpret_cast<float4*>(&Wl[idx]) = *reinterpret_cast<const float4*>(Bp + idx);
    __syncthreads();

    if (DOUT == 64) {
      const int rg = tid >> 4, cg = tid & 15;
      float acc[4][4] = {};
#pragma unroll 16
      for (int k = 0; k < 64; ++k) {
        float4 xv = *reinterpret_cast<const float4*>(&xT[k][rg * 4]);
        float4 wv = *reinterpret_cast<const float4*>(&Wl[k * 64 + cg * 4]);
        acc[0][0] += xv.x * wv.x; acc[0][1] += xv.x * wv.y; acc[0][2] += xv.x * wv.z; acc[0][3] += xv.x * wv.w;
        acc[1][0] += xv.y * wv.x; acc[1][1] += xv.y * wv.y; acc[1][2] += xv.y * wv.z; acc[1][3] += xv.y * wv.w;
        acc[2][0] += xv.z * wv.x; acc[2][1] += xv.z * wv.y; acc[2][2] += xv.z * wv.z; acc[2][3] += xv.z * wv.w;
        acc[3][0] += xv.w * wv.x; acc[3][1] += xv.w * wv.y; acc[3][2] += xv.w * wv.z; acc[3][3] += xv.w * wv.w;
      }
#pragma unroll
      for (int i = 0; i < 4; ++i) {
        long grow = row0 + rg * 4 + i;
        if (grow >= (long)NN) continue;
        if (ROOT) {
          float4 o;
          o.x = acc[i][0] + bias[cg * 4 + 0];
          o.y = acc[i][1] + bias[cg * 4 + 1];
          o.z = acc[i][2] + bias[cg * 4 + 2];
          o.w = acc[i][3] + bias[cg * 4 + 3];
          *reinterpret_cast<float4*>((float*)OUTv + grow * 64 + cg * 4) = o;
        } else {
          uint2 p;
          p.x = pack_h2(acc[i][0], acc[i][1]);
          p.y = pack_h2(acc[i][2], acc[i][3]);
          *reinterpret_cast<uint2*>((unsigned*)OUTv + ((long)rel * NN + grow) * 32 + cg * 2) = p;
        }
      }
    } else {  // DOUT == 16
      const int c0 = (tid & 7) * 2, r0 = (tid >> 3) * 2;
      float acc[2][2] = {};
#pragma unroll 16
      for (int k = 0; k < 64; ++k) {
        float2 xv = *reinterpret_cast<const float2*>(&xT[k][r0]);
        float2 wv = *reinterpret_cast<const float2*>(&Wl[k * 16 + c0]);
        acc[0][0] += xv.x * wv.x; acc[0][1] += xv.x * wv.y;
        acc[1][0] += xv.y * wv.x; acc[1][1] += xv.y * wv.y;
      }
#pragma unroll
      for (int i = 0; i < 2; ++i) {
        long grow = row0 + r0 + i;
        if (grow >= (long)NN) continue;
        if (ROOT) {
          float2 o;
          o.x = acc[i][0] + bias[c0 + 0];
          o.y = acc[i][1] + bias[c0 + 1];
          *reinterpret_cast<float2*>((float*)OUTv + grow * 16 + c0) = o;
        } else {
          ((unsigned*)OUTv)[((long)rel * NN + grow) * 8 + (c0 >> 1)] =
              pack_h2(acc[i][0], acc[i][1]);
        }
      }
    }
  }
}

// ---------------- gather layer 1: h1[d] (+)= sum_e XR[row_e]*rcp_e ----------------
// fp16 rows (128B = 32 lanes x uint); 8 dsts/wave, 2 edges/step.
__global__ __launch_bounds__(256) void gather1_k(float* __restrict__ h1,
                                                 const unsigned* __restrict__ XR,
                                                 const unsigned* __restrict__ keyptr,
                                                 const uint2* __restrict__ edata,
                                                 int rlo, int rhi, int lastpass) {
  const int tid = threadIdx.x, wv = tid >> 6, lane = tid & 63;
  const int half = lane >> 5, dim2 = lane & 31;
  const int dst0 = blockIdx.x * 32 + wv * 8;
  const long rbase = -(long)rlo * NN;

  unsigned a0[8], a1[8];
  float2 acc[8];
  int maxc = 0;
#pragma unroll
  for (int b = 0; b < 8; ++b) {
    int d = dst0 + b; if (d > NN - 1) d = NN - 1;
    a0[b] = keyptr[d * NREL + rlo];
    a1[b] = keyptr[d * NREL + rhi];
    int c = (int)(a1[b] - a0[b]);
    maxc = c > maxc ? c : maxc;
    acc[b].x = 0.f; acc[b].y = 0.f;
  }

  for (int s2 = 0; s2 < maxc; s2 += 2) {
#pragma unroll
    for (int b = 0; b < 8; ++b) {
      if ((unsigned)s2 < a1[b] - a0[b]) {
        unsigned e = a0[b] + (unsigned)s2 + (unsigned)half;
        bool valid = e < a1[b];
        unsigned ec = valid ? e : a1[b] - 1u;
        uint2 v = edata[ec];
        float rc = valid ? __uint_as_float(v.y) : 0.f;
        long row = (long)v.x + rbase;
        float2 xv = unpack_h2(XR[row * 32 + dim2]);
        acc[b].x += xv.x * rc;
        acc[b].y += xv.y * rc;
      }
    }
  }

#pragma unroll
  for (int b = 0; b < 8; ++b) {
    acc[b].x += __shfl_xor(acc[b].x, 32);
    acc[b].y += __shfl_xor(acc[b].y, 32);
    int d = dst0 + b;
    if (d < NN && lane < 32) {
      float2 base = *reinterpret_cast<const float2*>(&h1[(long)d * 64 + lane * 2]);
      float vx = base.x + acc[b].x, vy = base.y + acc[b].y;
      if (lastpass) { vx = fmaxf(vx, 0.f); vy = fmaxf(vy, 0.f); }
      float2 o; o.x = vx; o.y = vy;
      *reinterpret_cast<float2*>(&h1[(long)d * 64 + lane * 2]) = o;
    }
  }
}

// ---------------- gather layer 2: out[d] (+)= sum_e XR2[row_e]*rcp_e ----------------
// fp16 rows (32B = 8 lanes x uint); 8 dsts/wave, 8 edges/step.
__global__ __launch_bounds__(256) void gather2_k(float* __restrict__ out,
                                                 const unsigned* __restrict__ XR,
                                                 const unsigned* __restrict__ keyptr,
                                                 const uint2* __restrict__ edata,
                                                 int rlo, int rhi, int lastpass) {
  const int tid = threadIdx.x, wv = tid >> 6, lane = tid & 63;
  const int slot = lane >> 3, dp = lane & 7;
  const int dst0 = blockIdx.x * 32 + wv * 8;
  const long rbase = -(long)rlo * NN;

  unsigned a0[8], a1[8];
  float2 acc[8];
  int maxc = 0;
#pragma unroll
  for (int b = 0; b < 8; ++b) {
    int d = dst0 + b; if (d > NN - 1) d = NN - 1;
    a0[b] = keyptr[d * NREL + rlo];
    a1[b] = keyptr[d * NREL + rhi];
    int c = (int)(a1[b] - a0[b]);
    maxc = c > maxc ? c : maxc;
    acc[b].x = 0.f; acc[b].y = 0.f;
  }

  for (int s8 = 0; s8 < maxc; s8 += 8) {
#pragma unroll
    for (int b = 0; b < 8; ++b) {
      if ((unsigned)s8 < a1[b] - a0[b]) {
        unsigned e = a0[b] + (unsigned)s8 + (unsigned)slot;
        bool valid = e < a1[b];
        unsigned ec = valid ? e : a1[b] - 1u;
        uint2 v = edata[ec];
        float rc = valid ? __uint_as_float(v.y) : 0.f;
        long row = (long)v.x + rbase;
        float2 xv = unpack_h2(XR[row * 8 + dp]);
        acc[b].x += xv.x * rc;
        acc[b].y += xv.y * rc;
      }
    }
  }

#pragma unroll
  for (int b = 0; b < 8; ++b) {
    acc[b].x += __shfl_xor(acc[b].x, 8);
    acc[b].y += __shfl_xor(acc[b].y, 8);
    acc[b].x += __shfl_xor(acc[b].x, 16);
    acc[b].y += __shfl_xor(acc[b].y, 16);
    acc[b].x += __shfl_xor(acc[b].x, 32);
    acc[b].y += __shfl_xor(acc[b].y, 32);
    int d = dst0 + b;
    if (d < NN && lane < 8) {
      float2 base = *reinterpret_cast<const float2*>(&out[(long)d * 16 + lane * 2]);
      float vx = base.x + acc[b].x, vy = base.y + acc[b].y;
      if (lastpass) {
        vx = 1.0f / (1.0f + expf(-vx));
        vy = 1.0f / (1.0f + expf(-vy));
      }
      float2 o; o.x = vx; o.y = vy;
      *reinterpret_cast<float2*>(&out[(long)d * 16 + lane * 2]) = o;
    }
  }
}

extern "C" void kernel_launch(void* const* d_in, const int* in_sizes, int n_in,
                              void* d_out, int out_size, void* d_ws, size_t ws_size,
                              hipStream_t stream) {
  const int* ei = (const int*)d_in[0];
  const int* et = (const int*)d_in[1];
  const float* emb = (const float*)d_in[2];
  const float* W1 = (const float*)d_in[3];
  const float* root1 = (const float*)d_in[4];
  const float* bias1 = (const float*)d_in[5];
  const float* W2 = (const float*)d_in[6];
  const float* root2 = (const float*)d_in[7];
  const float* bias2 = (const float*)d_in[8];
  float* out = (float*)d_out;

  uint8_t* ws = (uint8_t*)d_ws;
  unsigned* C = (unsigned*)(ws + 0);              // 6.4 MB
  unsigned* part = (unsigned*)(ws + 6400000);     // 6.4 MB
  unsigned* keyptr = (unsigned*)(ws + 12800000);  // 6.4 MB + sentinel
  unsigned* cursor = (unsigned*)(ws + 19200512);  // 6.4 MB
  uint2* edata = (uint2*)(ws + 25600512);         // 12.8 MB
  unsigned* bsum = (unsigned*)(ws + 38400512);    // 2 KB
  unsigned* boff = (unsigned*)(ws + 38402560);    // 2 KB
  float* h1 = (float*)(ws + 38404608);            // 25.6 MB
  unsigned* XR = (unsigned*)(ws + 64004608);      // fp16 rows: G1*12.8 MB / G2*3.2 MB

  long avail = (long)ws_size - 64004608L;
  int G1 = (int)(avail / 12800000L); if (G1 < 1) G1 = 1; if (G1 > 8) G1 = 8;
  int G2 = (int)(avail / 3200000L);  if (G2 < 1) G2 = 1; if (G2 > 16) G2 = 16;

  const int nrow = (NN + 63) / 64;  // 1563
  const int ngat = (NN + 31) / 32;  // 3125

  hipMemsetAsync(C, 0, (size_t)NBINS * 4, stream);
  count_k<<<2048, 256, 0, stream>>>(ei, et, C);
  scan1_k<<<NSCAN_BLKS, 256, 0, stream>>>(C, part, bsum);
  scan2_k<<<1, 512, 0, stream>>>(bsum, boff);
  addoff_k<<<NBINS / 256, 256, 0, stream>>>(part, boff, keyptr, cursor);
  esort_k<<<2048, 256, 0, stream>>>(ei, et, C, cursor, edata);

  // ---- layer 1: root + relation chunks (fp16 XR, L3-resident per chunk) ----
  gemm_k<64, true><<<nrow, 256, 0, stream>>>(emb, root1, bias1, (void*)h1, 1);
  for (int rlo = 0; rlo < NREL; rlo += G1) {
    int rhi = rlo + G1 > NREL ? NREL : rlo + G1;
    gemm_k<64, false><<<nrow, 256, 0, stream>>>(emb, W1 + (long)rlo * 64 * 64,
                                                nullptr, (void*)XR, rhi - rlo);
    gather1_k<<<ngat, 256, 0, stream>>>(h1, XR, keyptr, edata, rlo, rhi,
                                        rhi == NREL ? 1 : 0);
  }

  // ---- layer 2 ----
  gemm_k<16, true><<<nrow, 256, 0, stream>>>(h1, root2, bias2, (void*)out, 1);
  for (int rlo = 0; rlo < NREL; rlo += G2) {
    int rhi = rlo + G2 > NREL ? NREL : rlo + G2;
    gemm_k<16, false><<<nrow, 256, 0, stream>>>(h1, W2 + (long)rlo * 64 * 16,
                                                nullptr, (void*)XR, rhi - rlo);
    gather2_k<<<ngat, 256, 0, stream>>>(out, XR, keyptr, edata, rlo, rhi,
                                        rhi == NREL ? 1 : 0);
  }
}

// Round 10
// 612.639 us; speedup vs baseline: 2.0990x; 1.2561x over previous
//
#include <hip/hip_runtime.h>
#include <hip/hip_fp16.h>

// RGCN 2-layer forward, MI355X — v9: XR transforms on MFMA f16 (x rounded to
// fp16 once; W split hi+lo fp16 -> 2 MFMAs, weight quantization eliminated),
// swapped operands (W^T x^T) so C/D lanes hold 4 consecutive dims -> uint2
// stores. fp16 XR + v7's proven dst-sorted gathers unchanged.

#define NN 100000
#define EE 1600000
#define NREL 16
#define NBINS (NN * NREL)
#define SCAN_BLK 4096
#define NSCAN_BLKS ((NBINS + SCAN_BLK - 1) / SCAN_BLK)  // 391

typedef _Float16 half8 __attribute__((ext_vector_type(8)));
typedef float f32x4 __attribute__((ext_vector_type(4)));

// ---------------- histogram ----------------
__global__ __launch_bounds__(256) void count_k(const int* __restrict__ ei,
                                               const int* __restrict__ et,
                                               unsigned* __restrict__ C) {
  int i = blockIdx.x * blockDim.x + threadIdx.x;
  int stride = gridDim.x * blockDim.x;
  for (; i < EE; i += stride) {
    int d = ei[EE + i];
    int t = et[i];
    atomicAdd(&C[d * NREL + t], 1u);
  }
}

// ---------------- scan level 1 ----------------
__global__ __launch_bounds__(256) void scan1_k(const unsigned* __restrict__ C,
                                               unsigned* __restrict__ part,
                                               unsigned* __restrict__ bsum) {
  __shared__ unsigned ssc[256];
  const int t = threadIdx.x, b = blockIdx.x;
  const int base = b * SCAN_BLK + t * 16;
  unsigned v[16];
  unsigned s = 0;
  const bool in = (base < NBINS);
  if (in) {
    const uint4* cp = reinterpret_cast<const uint4*>(C + base);
#pragma unroll
    for (int q = 0; q < 4; ++q) {
      uint4 u = cp[q];
      v[q * 4 + 0] = u.x; v[q * 4 + 1] = u.y; v[q * 4 + 2] = u.z; v[q * 4 + 3] = u.w;
      s += u.x + u.y + u.z + u.w;
    }
  } else {
#pragma unroll
    for (int q = 0; q < 16; ++q) v[q] = 0;
  }
  ssc[t] = s;
  __syncthreads();
  for (int off = 1; off < 256; off <<= 1) {
    unsigned add = (t >= off) ? ssc[t - off] : 0u;
    __syncthreads();
    ssc[t] += add;
    __syncthreads();
  }
  unsigned run = ssc[t] - s;
  if (in) {
#pragma unroll
    for (int q = 0; q < 16; ++q) { part[base + q] = run; run += v[q]; }
  }
  if (t == 255) bsum[b] = ssc[255];
}

// ---------------- scan level 2 ----------------
__global__ __launch_bounds__(512) void scan2_k(const unsigned* __restrict__ bsum,
                                               unsigned* __restrict__ boff) {
  __shared__ unsigned ssc[512];
  const int t = threadIdx.x;
  unsigned s = (t < NSCAN_BLKS) ? bsum[t] : 0u;
  ssc[t] = s;
  __syncthreads();
  for (int off = 1; off < 512; off <<= 1) {
    unsigned add = (t >= off) ? ssc[t - off] : 0u;
    __syncthreads();
    ssc[t] += add;
    __syncthreads();
  }
  if (t < NSCAN_BLKS) boff[t] = ssc[t] - s;
}

// ---------------- add offsets ----------------
__global__ __launch_bounds__(256) void addoff_k(const unsigned* __restrict__ part,
                                                const unsigned* __restrict__ boff,
                                                unsigned* __restrict__ keyptr,
                                                unsigned* __restrict__ cursor) {
  int i = blockIdx.x * blockDim.x + threadIdx.x;
  unsigned val = part[i] + boff[i >> 12];
  keyptr[i] = val;
  cursor[i] = val;
  if (i == 0) keyptr[NBINS] = EE;
}

// ---------------- scatter edges into sorted order; emit {rowidx, rcp} ----------------
__global__ __launch_bounds__(256) void esort_k(const int* __restrict__ ei,
                                               const int* __restrict__ et,
                                               const unsigned* __restrict__ C,
                                               unsigned* __restrict__ cursor,
                                               uint2* __restrict__ edata) {
  int i = blockIdx.x * blockDim.x + threadIdx.x;
  int stride = gridDim.x * blockDim.x;
  for (; i < EE; i += stride) {
    int s = ei[i];
    int d = ei[EE + i];
    int t = et[i];
    unsigned bin = (unsigned)d * NREL + t;
    unsigned p = atomicAdd(&cursor[bin], 1u);
    float rc = 1.0f / (float)C[bin];
    edata[p] = make_uint2((unsigned)(t * NN + s), __float_as_uint(rc));
  }
}

// ---------------- fp16 helpers ----------------
__device__ __forceinline__ unsigned pack_h2(float a, float b) {
  __half2 h = __floats2half2_rn(a, b);
  return *reinterpret_cast<unsigned*>(&h);
}
__device__ __forceinline__ float2 unpack_h2(unsigned u) {
  __half2 h = *reinterpret_cast<__half2*>(&u);
  return __half22float2(h);
}

// ---------------- prep: W1 -> MFMA A-fragments, hi+lo fp16 split ----------------
// A-frag layout (16x16x32, swapped: A = W^T): lane l holds dim = m*16+(l&15),
// k = kk*32 + (l>>4)*8 + j (j=0..7). Wf[((r*4+m)*2+kk)*64 + l][j].
__global__ __launch_bounds__(256) void prep1_k(const float* __restrict__ W1,
                                               _Float16* __restrict__ Hi,
                                               _Float16* __restrict__ Lo) {
  int idx = blockIdx.x * 256 + threadIdx.x;  // 16*4*2*64 = 8192
  if (idx >= 8192) return;
  int l = idx & 63, kk = (idx >> 6) & 1, m = (idx >> 7) & 3, r = idx >> 9;
  int dim = m * 16 + (l & 15);
  int k0 = kk * 32 + ((l >> 4) * 8);
#pragma unroll
  for (int j = 0; j < 8; ++j) {
    float v = W1[r * 4096 + (k0 + j) * 64 + dim];
    _Float16 h = (_Float16)v;
    Hi[idx * 8 + j] = h;
    Lo[idx * 8 + j] = (_Float16)(v - (float)h);
  }
}

__global__ __launch_bounds__(256) void prep2_k(const float* __restrict__ W2,
                                               _Float16* __restrict__ Hi,
                                               _Float16* __restrict__ Lo) {
  int idx = blockIdx.x * 256 + threadIdx.x;  // 16*2*64 = 2048
  if (idx >= 2048) return;
  int l = idx & 63, kk = (idx >> 6) & 1, r = idx >> 7;
  int dim = l & 15;
  int k0 = kk * 32 + ((l >> 4) * 8);
#pragma unroll
  for (int j = 0; j < 8; ++j) {
    float v = W2[r * 1024 + (k0 + j) * 16 + dim];
    _Float16 h = (_Float16)v;
    Hi[idx * 8 + j] = h;
    Lo[idx * 8 + j] = (_Float16)(v - (float)h);
  }
}

// ---------------- xr1: XR[rl][row][64] fp16 = x[row] @ W1[rlo+rl], MFMA ----------------
// 4 waves/block, 16 rows/wave. B-frag = x rows (fp16 once); A-frag = W hi/lo.
__global__ __launch_bounds__(256) void xr1_k(const float* __restrict__ x,
                                             const half8* __restrict__ Whi,
                                             const half8* __restrict__ Wlo,
                                             unsigned* __restrict__ XR,
                                             int rlo, int nrel) {
  const int tid = threadIdx.x, wv = tid >> 6, lane = tid & 63;
  const int row0 = blockIdx.x * 64 + wv * 16;
  const int xrow = row0 + (lane & 15);
  const int rowc = xrow < NN ? xrow : NN - 1;
  const int kb = (lane >> 4) * 8;
  const bool ok = xrow < NN;

  half8 bf[2];
#pragma unroll
  for (int kk = 0; kk < 2; ++kk) {
    const float* p = x + (long)rowc * 64 + kk * 32 + kb;
    float4 u0 = *reinterpret_cast<const float4*>(p);
    float4 u1 = *reinterpret_cast<const float4*>(p + 4);
    bf[kk][0] = (_Float16)u0.x; bf[kk][1] = (_Float16)u0.y;
    bf[kk][2] = (_Float16)u0.z; bf[kk][3] = (_Float16)u0.w;
    bf[kk][4] = (_Float16)u1.x; bf[kk][5] = (_Float16)u1.y;
    bf[kk][6] = (_Float16)u1.z; bf[kk][7] = (_Float16)u1.w;
  }

  for (int rl = 0; rl < nrel; ++rl) {
    const int r = rlo + rl;
    f32x4 acc[4];
#pragma unroll
    for (int m = 0; m < 4; ++m) { acc[m][0] = 0.f; acc[m][1] = 0.f; acc[m][2] = 0.f; acc[m][3] = 0.f; }
#pragma unroll
    for (int m = 0; m < 4; ++m) {
#pragma unroll
      for (int kk = 0; kk < 2; ++kk) {
        const int fi = ((r * 4 + m) * 2 + kk) * 64 + lane;
        half8 ah = Whi[fi];
        half8 al = Wlo[fi];
        acc[m] = __builtin_amdgcn_mfma_f32_16x16x32_f16(ah, bf[kk], acc[m], 0, 0, 0);
        acc[m] = __builtin_amdgcn_mfma_f32_16x16x32_f16(al, bf[kk], acc[m], 0, 0, 0);
      }
    }
    if (ok) {
      unsigned* rowp = XR + ((long)rl * NN + xrow) * 32;
#pragma unroll
      for (int m = 0; m < 4; ++m) {
        uint2 p;
        p.x = pack_h2(acc[m][0], acc[m][1]);
        p.y = pack_h2(acc[m][2], acc[m][3]);
        *reinterpret_cast<uint2*>(rowp + m * 8 + (lane >> 4) * 2) = p;
      }
    }
  }
}

// ---------------- xr2: XR2[rl][row][16] fp16 = h1[row] @ W2[rlo+rl], MFMA ----------------
__global__ __launch_bounds__(256) void xr2_k(const float* __restrict__ h1,
                                             const half8* __restrict__ Whi,
                                             const half8* __restrict__ Wlo,
                                             unsigned* __restrict__ XR,
                                             int rlo, int nrel) {
  const int tid = threadIdx.x, wv = tid >> 6, lane = tid & 63;
  const int row0 = blockIdx.x * 64 + wv * 16;
  const int xrow = row0 + (lane & 15);
  const int rowc = xrow < NN ? xrow : NN - 1;
  const int kb = (lane >> 4) * 8;
  const bool ok = xrow < NN;

  half8 bf[2];
#pragma unroll
  for (int kk = 0; kk < 2; ++kk) {
    const float* p = h1 + (long)rowc * 64 + kk * 32 + kb;
    float4 u0 = *reinterpret_cast<const float4*>(p);
    float4 u1 = *reinterpret_cast<const float4*>(p + 4);
    bf[kk][0] = (_Float16)u0.x; bf[kk][1] = (_Float16)u0.y;
    bf[kk][2] = (_Float16)u0.z; bf[kk][3] = (_Float16)u0.w;
    bf[kk][4] = (_Float16)u1.x; bf[kk][5] = (_Float16)u1.y;
    bf[kk][6] = (_Float16)u1.z; bf[kk][7] = (_Float16)u1.w;
  }

  for (int rl = 0; rl < nrel; ++rl) {
    const int r = rlo + rl;
    f32x4 acc;
    acc[0] = 0.f; acc[1] = 0.f; acc[2] = 0.f; acc[3] = 0.f;
#pragma unroll
    for (int kk = 0; kk < 2; ++kk) {
      const int fi = (r * 2 + kk) * 64 + lane;
      half8 ah = Whi[fi];
      half8 al = Wlo[fi];
      acc = __builtin_amdgcn_mfma_f32_16x16x32_f16(ah, bf[kk], acc, 0, 0, 0);
      acc = __builtin_amdgcn_mfma_f32_16x16x32_f16(al, bf[kk], acc, 0, 0, 0);
    }
    if (ok) {
      unsigned* rowp = XR + ((long)rl * NN + xrow) * 8;
      uint2 p;
      p.x = pack_h2(acc[0], acc[1]);
      p.y = pack_h2(acc[2], acc[3]);
      *reinterpret_cast<uint2*>(rowp + (lane >> 4) * 2) = p;
    }
  }
}

// ---------------- root GEMM (fp32 VALU, small) ----------------
template <int DOUT>
__global__ __launch_bounds__(256) void rootgemm_k(const float* __restrict__ A,
                                                  const float* __restrict__ B,
                                                  const float* __restrict__ bias,
                                                  float* __restrict__ OUT) {
  __shared__ float xT[64][64];
  __shared__ float Wl[64 * DOUT];
  const int tid = threadIdx.x;
  const long row0 = (long)blockIdx.x * 64;

#pragma unroll
  for (int i = 0; i < 4; ++i) {
    int idx = tid + i * 256;
    int r = idx & 63, kq = idx >> 6;
    float4 v = make_float4(0.f, 0.f, 0.f, 0.f);
    long g = row0 + r;
    if (g < (long)NN) v = *reinterpret_cast<const float4*>(A + g * 64 + kq * 4);
    xT[kq * 4 + 0][r] = v.x;
    xT[kq * 4 + 1][r] = v.y;
    xT[kq * 4 + 2][r] = v.z;
    xT[kq * 4 + 3][r] = v.w;
  }
  for (int idx = tid * 4; idx < 64 * DOUT; idx += 1024)
    *reinterpret_cast<float4*>(&Wl[idx]) = *reinterpret_cast<const float4*>(B + idx);
  __syncthreads();

  if (DOUT == 64) {
    const int rg = tid >> 4, cg = tid & 15;
    float acc[4][4] = {};
#pragma unroll 16
    for (int k = 0; k < 64; ++k) {
      float4 xv = *reinterpret_cast<const float4*>(&xT[k][rg * 4]);
      float4 wv = *reinterpret_cast<const float4*>(&Wl[k * 64 + cg * 4]);
      acc[0][0] += xv.x * wv.x; acc[0][1] += xv.x * wv.y; acc[0][2] += xv.x * wv.z; acc[0][3] += xv.x * wv.w;
      acc[1][0] += xv.y * wv.x; acc[1][1] += xv.y * wv.y; acc[1][2] += xv.y * wv.z; acc[1][3] += xv.y * wv.w;
      acc[2][0] += xv.z * wv.x; acc[2][1] += xv.z * wv.y; acc[2][2] += xv.z * wv.z; acc[2][3] += xv.z * wv.w;
      acc[3][0] += xv.w * wv.x; acc[3][1] += xv.w * wv.y; acc[3][2] += xv.w * wv.z; acc[3][3] += xv.w * wv.w;
    }
#pragma unroll
    for (int i = 0; i < 4; ++i) {
      long grow = row0 + rg * 4 + i;
      if (grow >= (long)NN) continue;
      float4 o;
      o.x = acc[i][0] + bias[cg * 4 + 0];
      o.y = acc[i][1] + bias[cg * 4 + 1];
      o.z = acc[i][2] + bias[cg * 4 + 2];
      o.w = acc[i][3] + bias[cg * 4 + 3];
      *reinterpret_cast<float4*>(OUT + grow * 64 + cg * 4) = o;
    }
  } else {
    const int c0 = (tid & 7) * 2, r0 = (tid >> 3) * 2;
    float acc[2][2] = {};
#pragma unroll 16
    for (int k = 0; k < 64; ++k) {
      float2 xv = *reinterpret_cast<const float2*>(&xT[k][r0]);
      float2 wv = *reinterpret_cast<const float2*>(&Wl[k * 16 + c0]);
      acc[0][0] += xv.x * wv.x; acc[0][1] += xv.x * wv.y;
      acc[1][0] += xv.y * wv.x; acc[1][1] += xv.y * wv.y;
    }
#pragma unroll
    for (int i = 0; i < 2; ++i) {
      long grow = row0 + r0 + i;
      if (grow >= (long)NN) continue;
      float2 o;
      o.x = acc[i][0] + bias[c0 + 0];
      o.y = acc[i][1] + bias[c0 + 1];
      *reinterpret_cast<float2*>(OUT + grow * 16 + c0) = o;
    }
  }
}

// ---------------- gather layer 1 (v7, proven) ----------------
__global__ __launch_bounds__(256) void gather1_k(float* __restrict__ h1,
                                                 const unsigned* __restrict__ XR,
                                                 const unsigned* __restrict__ keyptr,
                                                 const uint2* __restrict__ edata,
                                                 int rlo, int rhi, int lastpass) {
  const int tid = threadIdx.x, wv = tid >> 6, lane = tid & 63;
  const int half = lane >> 5, dim2 = lane & 31;
  const int dst0 = blockIdx.x * 32 + wv * 8;
  const long rbase = -(long)rlo * NN;

  unsigned a0[8], a1[8];
  float2 acc[8];
  int maxc = 0;
#pragma unroll
  for (int b = 0; b < 8; ++b) {
    int d = dst0 + b; if (d > NN - 1) d = NN - 1;
    a0[b] = keyptr[d * NREL + rlo];
    a1[b] = keyptr[d * NREL + rhi];
    int c = (int)(a1[b] - a0[b]);
    maxc = c > maxc ? c : maxc;
    acc[b].x = 0.f; acc[b].y = 0.f;
  }

  for (int s2 = 0; s2 < maxc; s2 += 2) {
#pragma unroll
    for (int b = 0; b < 8; ++b) {
      if ((unsigned)s2 < a1[b] - a0[b]) {
        unsigned e = a0[b] + (unsigned)s2 + (unsigned)half;
        bool valid = e < a1[b];
        unsigned ec = valid ? e : a1[b] - 1u;
        uint2 v = edata[ec];
        float rc = valid ? __uint_as_float(v.y) : 0.f;
        long row = (long)v.x + rbase;
        float2 xv = unpack_h2(XR[row * 32 + dim2]);
        acc[b].x += xv.x * rc;
        acc[b].y += xv.y * rc;
      }
    }
  }

#pragma unroll
  for (int b = 0; b < 8; ++b) {
    acc[b].x += __shfl_xor(acc[b].x, 32);
    acc[b].y += __shfl_xor(acc[b].y, 32);
    int d = dst0 + b;
    if (d < NN && lane < 32) {
      float2 base = *reinterpret_cast<const float2*>(&h1[(long)d * 64 + lane * 2]);
      float vx = base.x + acc[b].x, vy = base.y + acc[b].y;
      if (lastpass) { vx = fmaxf(vx, 0.f); vy = fmaxf(vy, 0.f); }
      float2 o; o.x = vx; o.y = vy;
      *reinterpret_cast<float2*>(&h1[(long)d * 64 + lane * 2]) = o;
    }
  }
}

// ---------------- gather layer 2 (v7, proven) ----------------
__global__ __launch_bounds__(256) void gather2_k(float* __restrict__ out,
                                                 const unsigned* __restrict__ XR,
                                                 const unsigned* __restrict__ keyptr,
                                                 const uint2* __restrict__ edata,
                                                 int rlo, int rhi, int lastpass) {
  const int tid = threadIdx.x, wv = tid >> 6, lane = tid & 63;
  const int slot = lane >> 3, dp = lane & 7;
  const int dst0 = blockIdx.x * 32 + wv * 8;
  const long rbase = -(long)rlo * NN;

  unsigned a0[8], a1[8];
  float2 acc[8];
  int maxc = 0;
#pragma unroll
  for (int b = 0; b < 8; ++b) {
    int d = dst0 + b; if (d > NN - 1) d = NN - 1;
    a0[b] = keyptr[d * NREL + rlo];
    a1[b] = keyptr[d * NREL + rhi];
    int c = (int)(a1[b] - a0[b]);
    maxc = c > maxc ? c : maxc;
    acc[b].x = 0.f; acc[b].y = 0.f;
  }

  for (int s8 = 0; s8 < maxc; s8 += 8) {
#pragma unroll
    for (int b = 0; b < 8; ++b) {
      if ((unsigned)s8 < a1[b] - a0[b]) {
        unsigned e = a0[b] + (unsigned)s8 + (unsigned)slot;
        bool valid = e < a1[b];
        unsigned ec = valid ? e : a1[b] - 1u;
        uint2 v = edata[ec];
        float rc = valid ? __uint_as_float(v.y) : 0.f;
        long row = (long)v.x + rbase;
        float2 xv = unpack_h2(XR[row * 8 + dp]);
        acc[b].x += xv.x * rc;
        acc[b].y += xv.y * rc;
      }
    }
  }

#pragma unroll
  for (int b = 0; b < 8; ++b) {
    acc[b].x += __shfl_xor(acc[b].x, 8);
    acc[b].y += __shfl_xor(acc[b].y, 8);
    acc[b].x += __shfl_xor(acc[b].x, 16);
    acc[b].y += __shfl_xor(acc[b].y, 16);
    acc[b].x += __shfl_xor(acc[b].x, 32);
    acc[b].y += __shfl_xor(acc[b].y, 32);
    int d = dst0 + b;
    if (d < NN && lane < 8) {
      float2 base = *reinterpret_cast<const float2*>(&out[(long)d * 16 + lane * 2]);
      float vx = base.x + acc[b].x, vy = base.y + acc[b].y;
      if (lastpass) {
        vx = 1.0f / (1.0f + expf(-vx));
        vy = 1.0f / (1.0f + expf(-vy));
      }
      float2 o; o.x = vx; o.y = vy;
      *reinterpret_cast<float2*>(&out[(long)d * 16 + lane * 2]) = o;
    }
  }
}

extern "C" void kernel_launch(void* const* d_in, const int* in_sizes, int n_in,
                              void* d_out, int out_size, void* d_ws, size_t ws_size,
                              hipStream_t stream) {
  const int* ei = (const int*)d_in[0];
  const int* et = (const int*)d_in[1];
  const float* emb = (const float*)d_in[2];
  const float* W1 = (const float*)d_in[3];
  const float* root1 = (const float*)d_in[4];
  const float* bias1 = (const float*)d_in[5];
  const float* W2 = (const float*)d_in[6];
  const float* root2 = (const float*)d_in[7];
  const float* bias2 = (const float*)d_in[8];
  float* out = (float*)d_out;

  uint8_t* ws = (uint8_t*)d_ws;
  unsigned* C = (unsigned*)(ws + 0);                // 6.4 MB
  unsigned* part = (unsigned*)(ws + 6400000);       // 6.4 MB
  unsigned* keyptr = (unsigned*)(ws + 12800000);    // 6.4 MB + sentinel
  unsigned* cursor = (unsigned*)(ws + 19200512);    // 6.4 MB
  uint2* edata = (uint2*)(ws + 25600512);           // 12.8 MB
  unsigned* bsum = (unsigned*)(ws + 38400512);      // 2 KB
  unsigned* boff = (unsigned*)(ws + 38402560);      // 2 KB
  _Float16* Wf1hi = (_Float16*)(ws + 38404608);     // 128 KB
  _Float16* Wf1lo = (_Float16*)(ws + 38535680);     // 128 KB
  _Float16* Wf2hi = (_Float16*)(ws + 38666752);     // 32 KB
  _Float16* Wf2lo = (_Float16*)(ws + 38699520);     // 32 KB
  float* h1 = (float*)(ws + 38732288);              // 25.6 MB
  unsigned* XR = (unsigned*)(ws + 64332288);        // fp16 rows

  long avail = (long)ws_size - 64332288L;
  int G1 = (int)(avail / 12800000L); if (G1 < 1) G1 = 1; if (G1 > 8) G1 = 8;
  int G2 = (int)(avail / 3200000L);  if (G2 < 1) G2 = 1; if (G2 > 16) G2 = 16;

  const int nrow = (NN + 63) / 64;  // 1563
  const int ngat = (NN + 31) / 32;  // 3125

  hipMemsetAsync(C, 0, (size_t)NBINS * 4, stream);
  count_k<<<2048, 256, 0, stream>>>(ei, et, C);
  prep1_k<<<32, 256, 0, stream>>>(W1, Wf1hi, Wf1lo);
  prep2_k<<<8, 256, 0, stream>>>(W2, Wf2hi, Wf2lo);
  scan1_k<<<NSCAN_BLKS, 256, 0, stream>>>(C, part, bsum);
  scan2_k<<<1, 512, 0, stream>>>(bsum, boff);
  addoff_k<<<NBINS / 256, 256, 0, stream>>>(part, boff, keyptr, cursor);
  esort_k<<<2048, 256, 0, stream>>>(ei, et, C, cursor, edata);

  // ---- layer 1 ----
  rootgemm_k<64><<<nrow, 256, 0, stream>>>(emb, root1, bias1, h1);
  for (int rlo = 0; rlo < NREL; rlo += G1) {
    int rhi = rlo + G1 > NREL ? NREL : rlo + G1;
    xr1_k<<<nrow, 256, 0, stream>>>(emb, (const half8*)Wf1hi, (const half8*)Wf1lo,
                                    XR, rlo, rhi - rlo);
    gather1_k<<<ngat, 256, 0, stream>>>(h1, XR, keyptr, edata, rlo, rhi,
                                        rhi == NREL ? 1 : 0);
  }

  // ---- layer 2 ----
  rootgemm_k<16><<<nrow, 256, 0, stream>>>(h1, root2, bias2, out);
  for (int rlo = 0; rlo < NREL; rlo += G2) {
    int rhi = rlo + G2 > NREL ? NREL : rlo + G2;
    xr2_k<<<nrow, 256, 0, stream>>>(h1, (const half8*)Wf2hi, (const half8*)Wf2lo,
                                    XR, rlo, rhi - rlo);
    gather2_k<<<ngat, 256, 0, stream>>>(out, XR, keyptr, edata, rlo, rhi,
                                        rhi == NREL ? 1 : 0);
  }
}